// Round 11
// baseline (754.582 us; speedup 1.0000x reference)
//
#include <hip/hip_runtime.h>

#define D 128
#define NCK 512           // edge chunks
#define RPB 32            // rows per bucket
#define BCAP 1024         // fixed region per bucket (mean 512, +22 sigma)
#define SCANW 2048        // padded bucket width (nbuck = 1563)
#define CHUNKCAP 1600     // LDS staging per chunk (chunk <= 1563)
#define RAWB 17408        // union: tile int[64][65] (16.6KB) | As[64][136] (17.4KB)

typedef short short8 __attribute__((ext_vector_type(8)));
typedef float v4f __attribute__((ext_vector_type(4)));
typedef float float2v __attribute__((ext_vector_type(2)));

static __device__ __forceinline__ unsigned short f2bf(float f) {
    unsigned u = __builtin_bit_cast(unsigned, f);
    u = (u + 0x7FFFu + ((u >> 16) & 1u)) >> 16;   // RNE
    return (unsigned short)u;
}

// ---- L1: blocks [0,128): Wt prep; blocks [128,128+NCK): per-chunk histogram
__global__ __launch_bounds__(256) void wt_hist(
    const float* __restrict__ W, const float* __restrict__ Wr,
    unsigned short* __restrict__ Wt,
    const int* __restrict__ rows, int* __restrict__ cntT,
    int E, int nbuck, int chunk)
{
    __shared__ int hist[SCANW];
    const int t = threadIdx.x;
    if ((int)blockIdx.x < 128) {
        const int gid = (int)blockIdx.x * 256 + t;   // < 32768
        const int k  = gid >> 8;
        const int nn = gid & 255;
        const float v = (nn < D) ? W[k * D + nn] : Wr[k * D + (nn - D)];
        Wt[nn * D + k] = f2bf(v);
        return;
    }
    const int c = (int)blockIdx.x - 128;
    #pragma unroll
    for (int j = 0; j < SCANW / 256; ++j) hist[t + j * 256] = 0;
    __syncthreads();
    const int base = c * chunk;
    const int endv = min(base + chunk, E);
    for (int e = base + t; e < endv; e += 256)
        atomicAdd(&hist[rows[e] >> 5], 1);
    __syncthreads();
    for (int i = t; i < nbuck; i += 256) cntT[(size_t)c * nbuck + i] = hist[i];
}

// ---- L2: blocks [0,nScanB): per-bucket chunk-prefix scan (tile transpose);
//          rest: dual GEMM support=x@W, rootbuf=x@Wr
__global__ __launch_bounds__(256) void scan_gemm(
    const int* __restrict__ cntT, unsigned short* __restrict__ scatOff,
    int* __restrict__ bucketTot,
    const float* __restrict__ x, const unsigned short* __restrict__ Wt,
    unsigned short* __restrict__ support, unsigned short* __restrict__ rootbuf,
    int M, int nbuck, int nScanB)
{
    __shared__ __align__(16) char raw[RAWB];
    const int t = threadIdx.x;

    if ((int)blockIdx.x < nScanB) {
        // -------- scan branch: 64 buckets per block, serial over 8 c-tiles --
        int (*tile)[65] = (int (*)[65])raw;
        const int bb = (int)blockIdx.x * 64;
        int carry = 0;                               // live in threads t<64
        for (int j = 0; j < NCK / 64; ++j) {
            for (int i = t; i < 64 * 64; i += 256) {
                const int cr = i >> 6, bc = i & 63;
                const int b = bb + bc, c = j * 64 + cr;
                tile[cr][bc] = (b < nbuck) ? cntT[(size_t)c * nbuck + b] : 0;
            }
            __syncthreads();
            if (t < 64) {
                int run = carry;
                for (int cr = 0; cr < 64; ++cr) {
                    const int v = tile[cr][t];
                    tile[cr][t] = run;               // exclusive offset
                    run += v;
                }
                carry = run;
            }
            __syncthreads();
            for (int i = t; i < 64 * 64; i += 256) {
                const int cr = i >> 6, bc = i & 63;
                const int b = bb + bc, c = j * 64 + cr;
                if (b < nbuck)
                    scatOff[(size_t)c * nbuck + b] =
                        (unsigned short)min(tile[cr][bc], 0xFFFF);
            }
            __syncthreads();
        }
        if (t < 64 && bb + t < nbuck) bucketTot[bb + t] = carry;
        return;
    }

    // -------- GEMM branch --------
    unsigned short (*As)[136] = (unsigned short (*)[136])raw;
    const int lane = t & 63, w = t >> 6;
    const int nl = lane & 15, quad = lane >> 4;
    const int rowBase = ((int)blockIdx.x - nScanB) * 64;

    {
        const int r = t & 63;
        const int seg = t >> 6;
        const int row = rowBase + r;
        unsigned short tmp[32];
        if (row < M) {
            const float4* src = (const float4*)(x + (size_t)row * D + seg * 32);
            #pragma unroll
            for (int j = 0; j < 8; ++j) {
                const float4 v = src[j];
                tmp[j * 4 + 0] = f2bf(v.x); tmp[j * 4 + 1] = f2bf(v.y);
                tmp[j * 4 + 2] = f2bf(v.z); tmp[j * 4 + 3] = f2bf(v.w);
            }
        } else {
            #pragma unroll
            for (int j = 0; j < 32; ++j) tmp[j] = 0;
        }
        #pragma unroll
        for (int j = 0; j < 4; ++j)
            *(short8*)&As[r][seg * 32 + j * 8] = *(const short8*)&tmp[j * 8];
    }

    short8 bfrag[4][4];
    {
        const unsigned short* wbase = Wt + (size_t)(w * 64 + nl) * D + quad * 8;
        #pragma unroll
        for (int nt = 0; nt < 4; ++nt)
            #pragma unroll
            for (int c = 0; c < 4; ++c)
                bfrag[c][nt] = *(const short8*)(wbase + (size_t)nt * 16 * D + c * 32);
    }
    __syncthreads();

    v4f acc[4][4] = {};
    #pragma unroll
    for (int c = 0; c < 4; ++c) {
        short8 afr[4];
        #pragma unroll
        for (int mt = 0; mt < 4; ++mt)
            afr[mt] = *(const short8*)&As[mt * 16 + nl][c * 32 + quad * 8];
        #pragma unroll
        for (int mt = 0; mt < 4; ++mt)
            #pragma unroll
            for (int nt = 0; nt < 4; ++nt)
                acc[mt][nt] = __builtin_amdgcn_mfma_f32_16x16x32_bf16(
                    afr[mt], bfrag[c][nt], acc[mt][nt], 0, 0, 0);
    }

    const int cbase = (w & 1) * 64;
    unsigned short* dst = (w < 2) ? support : rootbuf;
    #pragma unroll
    for (int mt = 0; mt < 4; ++mt)
        #pragma unroll
        for (int reg = 0; reg < 4; ++reg) {
            const int row = rowBase + mt * 16 + quad * 4 + reg;
            if (row < M) {
                #pragma unroll
                for (int nt = 0; nt < 4; ++nt)
                    dst[(size_t)row * D + cbase + nt * 16 + nl] = f2bf(acc[mt][nt][reg]);
            }
        }
}

// ---- L3: scatter — LDS counting-sort per chunk, write runs to exact global
//          positions in per-bucket regions; XCD-swizzled chunk mapping so
//          same-destination-line writers share one XCD's L2 (lines merge).
__global__ __launch_bounds__(256) void scatter(
    const int* __restrict__ rows, const int* __restrict__ cols,
    const float* __restrict__ vals, const unsigned short* __restrict__ scatOff,
    int2* __restrict__ sortedG, int E, int nbuck, int chunk)
{
    __shared__ int hist[SCANW];
    __shared__ int cur[SCANW];
    __shared__ int2 stg[CHUNKCAP];
    __shared__ int wsumK[4];
    const int t = threadIdx.x;
    const int lane = t & 63, w = t >> 6;
    const int c = ((int)blockIdx.x & 7) * 64 + ((int)blockIdx.x >> 3); // XCD-contig

    #pragma unroll
    for (int j = 0; j < SCANW / 256; ++j) hist[t + j * 256] = 0;
    __syncthreads();

    const int base = c * chunk;
    const int endv = min(base + chunk, E);
    for (int e = base + t; e < endv; e += 256)
        atomicAdd(&hist[rows[e] >> 5], 1);
    __syncthreads();

    int lv[8], ssum = 0;
    #pragma unroll
    for (int j = 0; j < 8; ++j) { lv[j] = hist[8 * t + j]; ssum += lv[j]; }
    int s = ssum;
    #pragma unroll
    for (int d = 1; d < 64; d <<= 1) {
        const int u = __shfl_up(s, d);
        if (lane >= d) s += u;
    }
    if (lane == 63) wsumK[w] = s;
    __syncthreads();
    int woff = 0;
    #pragma unroll
    for (int j = 0; j < 4; ++j) if (j < w) woff += wsumK[j];
    int run = woff + s - ssum;
    int lbase[8];
    #pragma unroll
    for (int j = 0; j < 8; ++j) { lbase[j] = run; cur[8 * t + j] = run; run += lv[j]; }
    __syncthreads();

    for (int e = base + t; e < endv; e += 256) {
        const int r  = rows[e];
        const int cc = cols[e];
        const float v = vals[e];
        const int pos = atomicAdd(&cur[r >> 5], 1);
        stg[pos] = make_int2(((r & (RPB - 1)) << 16) | cc, __float_as_int(v));
    }
    __syncthreads();

    // copy each owned bucket's run to its exact global slot
    #pragma unroll
    for (int j = 0; j < 8; ++j) {
        const int b = 8 * t + j;
        if (b < nbuck && lv[j] > 0) {
            const int go = scatOff[(size_t)c * nbuck + b];
            int2* dst = sortedG + (size_t)b * BCAP + go;
            const int lim = min(lv[j], BCAP - go);
            for (int k = 0; k < lim; ++k) dst[k] = stg[lbase[j] + k];
        }
    }
}

// ---- L4: aggregate — contiguous bucket read, ds_add_f32 into acc[32][128],
//          epilogue adds root and writes out. No row-sort.
__global__ __launch_bounds__(256) void aggregate(
    const int* __restrict__ bucketTot, const int2* __restrict__ sortedG,
    const unsigned short* __restrict__ support,
    const unsigned short* __restrict__ rootbuf,
    float* __restrict__ out, int M)
{
    __shared__ int2 stage[BCAP];        // 8 KB
    __shared__ float acc[RPB][D];       // 16 KB
    const int b = blockIdx.x, t = threadIdx.x;
    const int lane = t & 63, w = t >> 6;

    const int T = min(bucketTot[b], BCAP);
    const int2* src = sortedG + (size_t)b * BCAP;
    for (int i = t; i < T; i += 256) stage[i] = src[i];
    float* af = (float*)acc;
    #pragma unroll
    for (int i = 0; i < (RPB * D) / 256; ++i) af[t + i * 256] = 0.f;
    __syncthreads();

    // wave-cooperative, 8-deep batched gather + LDS atomic accumulate
    for (int i = w * 8; i < T; i += 32) {
        const int nb = min(8, T - i);
        int2 ed[8];
        #pragma unroll
        for (int j = 0; j < 8; ++j) ed[j] = stage[i + (j < nb ? j : nb - 1)];
        unsigned p[8];
        #pragma unroll
        for (int j = 0; j < 8; ++j)
            p[j] = *(const unsigned*)(support +
                     (size_t)(ed[j].x & 0xFFFF) * D + lane * 2);
        #pragma unroll
        for (int j = 0; j < 8; ++j) {
            if (j < nb) {
                const int rib = ed[j].x >> 16;
                const float v = __int_as_float(ed[j].y);
                atomicAdd(&acc[rib][lane * 2],
                          __builtin_bit_cast(float, p[j] << 16) * v);
                atomicAdd(&acc[rib][lane * 2 + 1],
                          __builtin_bit_cast(float, p[j] & 0xFFFF0000u) * v);
            }
        }
    }
    __syncthreads();

    for (int r = w; r < RPB; r += 4) {
        const int row = b * RPB + r;
        if (row >= M) break;
        const unsigned pr = *(const unsigned*)(rootbuf + (size_t)row * D + lane * 2);
        float2v ov;
        ov.x = acc[r][lane * 2]     + __builtin_bit_cast(float, pr << 16);
        ov.y = acc[r][lane * 2 + 1] + __builtin_bit_cast(float, pr & 0xFFFF0000u);
        __builtin_nontemporal_store(ov, (float2v*)(out + (size_t)row * D + lane * 2));
    }
}

extern "C" void kernel_launch(void* const* d_in, const int* in_sizes, int n_in,
                              void* d_out, int out_size, void* d_ws, size_t ws_size,
                              hipStream_t stream) {
    const float* x     = (const float*)d_in[0];
    const int*   erows = (const int*)d_in[1];
    const int*   ecols = (const int*)d_in[2];
    const float* evals = (const float*)d_in[3];
    const float* W     = (const float*)d_in[4];
    const float* Wr    = (const float*)d_in[5];
    float* out = (float*)d_out;

    const int M = in_sizes[0] / D;   // 50000
    const int E = in_sizes[1];       // 800000

    const int nbuck  = (M + RPB - 1) / RPB;        // 1563
    const int chunk  = (E + NCK - 1) / NCK;        // 1563
    const int nGemm  = (M + 63) / 64;              // 782
    const int nScanB = (nbuck + 63) / 64;          // 25

    // ws layout
    unsigned short* support = (unsigned short*)d_ws;             // M*D bf16
    unsigned short* rootbuf = support + (size_t)M * D;           // M*D bf16
    unsigned short* Wt      = rootbuf + (size_t)M * D;           // 2*D*D bf16
    int*  cntT      = (int*)(Wt + 2 * D * D);                    // NCK*nbuck
    int*  bucketTot = cntT + (size_t)NCK * nbuck;                // nbuck
    unsigned short* scatOff = (unsigned short*)(bucketTot + nbuck + 2); // NCK*nbuck
    size_t soEnd = (size_t)NCK * nbuck;  soEnd += soEnd & 1;     // align to 4B
    int2* sortedG  = (int2*)(scatOff + soEnd + 2);               // nbuck*BCAP

    wt_hist<<<128 + NCK, 256, 0, stream>>>(W, Wr, Wt, erows, cntT, E, nbuck, chunk);
    scan_gemm<<<nScanB + nGemm, 256, 0, stream>>>(
        cntT, scatOff, bucketTot, x, Wt, support, rootbuf, M, nbuck, nScanB);
    scatter<<<NCK, 256, 0, stream>>>(erows, ecols, evals, scatOff, sortedG,
                                     E, nbuck, chunk);
    aggregate<<<nbuck, 256, 0, stream>>>(bucketTot, sortedG, support, rootbuf,
                                         out, M);
}

// Round 12
// 206.149 us; speedup vs baseline: 3.6604x; 3.6604x over previous
//
#include <hip/hip_runtime.h>

#define D 128
#define NCK 512           // edge chunks (binsort blocks in fused K1)
#define RPB 32            // rows per bucket
#define CHUNKCAP 1600     // LDS staging per chunk (chunk <= 1563)
#define BCAP 1024         // per-bucket edge capacity (mean 512, +22 sigma)
#define SCANW 2048        // padded bucket-scan width (nbuck = 1563)
#define RAWB 29184        // union LDS: max(2*SCANW*4 + CHUNKCAP*8, 64*136*2)

typedef short short8 __attribute__((ext_vector_type(8)));
typedef float v4f __attribute__((ext_vector_type(4)));
typedef float float2v __attribute__((ext_vector_type(2)));

static __device__ __forceinline__ unsigned short f2bf(float f) {
    unsigned u = __builtin_bit_cast(unsigned, f);
    u = (u + 0x7FFFu + ((u >> 16) & 1u)) >> 16;   // RNE
    return (unsigned short)u;
}

// ---- K0: Wt[n][k] = (W||Wr)[k][n] bf16 -------------------------------------
__global__ __launch_bounds__(256) void wt_prep(
    const float* __restrict__ W, const float* __restrict__ Wr,
    unsigned short* __restrict__ Wt)
{
    const int gid = (int)blockIdx.x * 256 + (int)threadIdx.x;   // < 32768
    const int k  = gid >> 8;
    const int nn = gid & 255;
    const float v = (nn < D) ? W[k * D + nn] : Wr[k * D + (nn - D)];
    Wt[nn * D + k] = f2bf(v);
}

// ---- K1: fused — blocks [0,NCK): per-chunk binsort; rest: dual GEMM --------
__global__ __launch_bounds__(256) void prep_gemm(
    const int* __restrict__ rows, const int* __restrict__ cols,
    const float* __restrict__ vals,
    unsigned* __restrict__ pkT, int2* __restrict__ sortedB,
    const float* __restrict__ x, const unsigned short* __restrict__ Wt,
    unsigned short* __restrict__ support, unsigned short* __restrict__ rootbuf,
    int M, int E, int nbuck, int chunk)
{
    __shared__ __align__(16) char raw[RAWB];
    __shared__ int wsumK[4];
    const int t = threadIdx.x;
    const int lane = t & 63, w = t >> 6;

    if ((int)blockIdx.x < NCK) {
        // ---------------- binsort branch ----------------
        int* hist = (int*)raw;                       // SCANW
        int* cur  = hist + SCANW;                    // SCANW
        int2* stg = (int2*)(raw + 2 * SCANW * 4);    // CHUNKCAP
        const int c = blockIdx.x;

        #pragma unroll
        for (int j = 0; j < SCANW / 256; ++j) hist[t + j * 256] = 0;
        __syncthreads();

        const int base = c * chunk;
        const int endv = min(base + chunk, E);
        for (int e = base + t; e < endv; e += 256)
            atomicAdd(&hist[rows[e] >> 5], 1);
        __syncthreads();

        // thread t owns 8 contiguous buckets [8t, 8t+8)
        int lv[8];
        int ssum = 0;
        #pragma unroll
        for (int j = 0; j < 8; ++j) { lv[j] = hist[8 * t + j]; ssum += lv[j]; }
        int s = ssum;                                // wave inclusive scan
        #pragma unroll
        for (int d = 1; d < 64; d <<= 1) {
            const int u = __shfl_up(s, d);
            if (lane >= d) s += u;
        }
        if (lane == 63) wsumK[w] = s;
        __syncthreads();
        int woff = 0;
        #pragma unroll
        for (int j = 0; j < 4; ++j) if (j < w) woff += wsumK[j];
        int run = woff + s - ssum;                   // exclusive base
        #pragma unroll
        for (int j = 0; j < 8; ++j) {
            const int idx = 8 * t + j;
            cur[idx] = run;
            if (idx < nbuck)
                pkT[(size_t)c * nbuck + idx] =
                    ((unsigned)lv[j] << 16) | (unsigned)run;
            run += lv[j];
        }
        __syncthreads();

        for (int e = base + t; e < endv; e += 256) {
            const int r  = rows[e];
            const int cc = cols[e];
            const float v = vals[e];
            const int pos = atomicAdd(&cur[r >> 5], 1);
            stg[pos] = make_int2(((r & (RPB - 1)) << 16) | cc, __float_as_int(v));
        }
        __syncthreads();

        const int n = endv - base;
        for (int k = t; k < n; k += 256)
            sortedB[(size_t)base + k] = stg[k];   // contiguous full-line writes
        return;
    }

    // ---------------- GEMM branch ----------------
    unsigned short (*As)[136] = (unsigned short (*)[136])raw;
    const int nl = lane & 15, quad = lane >> 4;
    const int rowBase = ((int)blockIdx.x - NCK) * 64;

    {
        const int r = t & 63;
        const int seg = t >> 6;
        const int row = rowBase + r;
        unsigned short tmp[32];
        if (row < M) {
            const float4* src = (const float4*)(x + (size_t)row * D + seg * 32);
            #pragma unroll
            for (int j = 0; j < 8; ++j) {
                const float4 v = src[j];
                tmp[j * 4 + 0] = f2bf(v.x); tmp[j * 4 + 1] = f2bf(v.y);
                tmp[j * 4 + 2] = f2bf(v.z); tmp[j * 4 + 3] = f2bf(v.w);
            }
        } else {
            #pragma unroll
            for (int j = 0; j < 32; ++j) tmp[j] = 0;
        }
        #pragma unroll
        for (int j = 0; j < 4; ++j)
            *(short8*)&As[r][seg * 32 + j * 8] = *(const short8*)&tmp[j * 8];
    }

    short8 bfrag[4][4];
    {
        const unsigned short* wbase = Wt + (size_t)(w * 64 + nl) * D + quad * 8;
        #pragma unroll
        for (int nt = 0; nt < 4; ++nt)
            #pragma unroll
            for (int c = 0; c < 4; ++c)
                bfrag[c][nt] = *(const short8*)(wbase + (size_t)nt * 16 * D + c * 32);
    }
    __syncthreads();

    v4f acc[4][4] = {};
    #pragma unroll
    for (int c = 0; c < 4; ++c) {
        short8 afr[4];
        #pragma unroll
        for (int mt = 0; mt < 4; ++mt)
            afr[mt] = *(const short8*)&As[mt * 16 + nl][c * 32 + quad * 8];
        #pragma unroll
        for (int mt = 0; mt < 4; ++mt)
            #pragma unroll
            for (int nt = 0; nt < 4; ++nt)
                acc[mt][nt] = __builtin_amdgcn_mfma_f32_16x16x32_bf16(
                    afr[mt], bfrag[c][nt], acc[mt][nt], 0, 0, 0);
    }

    const int cbase = (w & 1) * 64;
    unsigned short* dst = (w < 2) ? support : rootbuf;
    #pragma unroll
    for (int mt = 0; mt < 4; ++mt)
        #pragma unroll
        for (int reg = 0; reg < 4; ++reg) {
            const int row = rowBase + mt * 16 + quad * 4 + reg;
            if (row < M) {
                #pragma unroll
                for (int nt = 0; nt < 4; ++nt)
                    dst[(size_t)row * D + cbase + nt * 16 + nl] = f2bf(acc[mt][nt][reg]);
            }
        }
}

// ---- K1.5: transpose pkT[c][b] -> pkTt[b][c] (coalesced both sides) --------
__global__ __launch_bounds__(256) void transpose_pk(
    const unsigned* __restrict__ pkT, unsigned* __restrict__ pkTt, int nbuck)
{
    __shared__ unsigned tile[64][65];
    const int cb = (int)blockIdx.x & 7;          // NCK/64 = 8
    const int bb = (int)blockIdx.x >> 3;
    const int t = threadIdx.x;
    for (int i = t; i < 64 * 64; i += 256) {
        const int lc = i & 63, lr = i >> 6;
        const int b = bb * 64 + lc, c = cb * 64 + lr;
        tile[lr][lc] = (b < nbuck) ? pkT[(size_t)c * nbuck + b] : 0u;
    }
    __syncthreads();
    for (int i = t; i < 64 * 64; i += 256) {
        const int lc = i & 63, lr = i >> 6;
        const int b = bb * 64 + lr, c = cb * 64 + lc;
        if (b < nbuck) pkTt[(size_t)b * NCK + c] = tile[lc][lr];
    }
}

// ---- K2: per-bucket (32 rows): stage -> LDS row-sort -> QUARTER-PHASED
//          register gather-reduce (64B/row per phase; 3.2MB hot set fits L2)
__global__ __launch_bounds__(256) void sort_aggregate(
    const unsigned* __restrict__ pkTt, const int2* __restrict__ sortedB,
    const unsigned short* __restrict__ support,
    const unsigned short* __restrict__ rootbuf,
    float* __restrict__ out, int M, int nbuck, int chunk)
{
    __shared__ int2 stage[BCAP];        // 8 KB
    __shared__ unsigned rowList[BCAP];  // 4 KB
    __shared__ int wsum[4];
    __shared__ int rh[RPB];
    __shared__ int rs[RPB + 1];
    __shared__ int rcur[RPB];
    const int b = blockIdx.x, t = threadIdx.x;
    const int lane = t & 63, w = t >> 6;

    // coalesced table read: thread t owns chunks 2t, 2t+1
    const uint2 pk2 = *(const uint2*)(pkTt + (size_t)b * NCK + 2 * t);
    const int cnt0 = (int)(pk2.x >> 16), off0 = (int)(pk2.x & 0xFFFFu);
    const int cnt1 = (int)(pk2.y >> 16), off1 = (int)(pk2.y & 0xFFFFu);
    int s = cnt0 + cnt1;                 // wave inclusive scan over pair-sums
    #pragma unroll
    for (int d = 1; d < 64; d <<= 1) {
        const int u = __shfl_up(s, d);
        if (lane >= d) s += u;
    }
    if (lane == 63) wsum[w] = s;
    __syncthreads();
    int woff = 0, tot = 0;
    #pragma unroll
    for (int j = 0; j < 4; ++j) { const int v = wsum[j]; if (j < w) woff += v; tot += v; }
    const int incl = woff + s;
    const int base1 = incl - cnt1;
    const int base0 = base1 - cnt0;
    {
        const int2* src = sortedB + (size_t)(2 * t) * chunk + off0;
        int lim = min(base0 + cnt0, BCAP) - base0; if (lim < 0) lim = 0;
        for (int k = 0; k < lim; ++k) stage[base0 + k] = src[k];
    }
    {
        const int2* src = sortedB + (size_t)(2 * t + 1) * chunk + off1;
        int lim = min(base1 + cnt1, BCAP) - base1; if (lim < 0) lim = 0;
        for (int k = 0; k < lim; ++k) stage[base1 + k] = src[k];
    }
    if (t < RPB) rh[t] = 0;
    __syncthreads();

    const int T = min(tot, BCAP);
    for (int e = t; e < T; e += 256) atomicAdd(&rh[stage[e].x >> 16], 1);
    __syncthreads();
    if (t < 64) {                        // row scan (32 wide) in first wave
        const int mine = (t < RPB) ? rh[t] : 0;
        int v = mine;
        #pragma unroll
        for (int d = 1; d < RPB; d <<= 1) {
            const int u = __shfl_up(v, d);
            if (lane >= d) v += u;
        }
        if (t < RPB) {
            rs[t] = v - mine; rcur[t] = v - mine;
            if (t == RPB - 1) rs[RPB] = v;
        }
    }
    __syncthreads();
    for (int e = t; e < T; e += 256) {
        const int2 ed = stage[e];
        const int rib = ed.x >> 16;
        const int pos = atomicAdd(&rcur[rib], 1);
        rowList[pos] = ((unsigned)f2bf(__int_as_float(ed.y)) << 16)
                     | (unsigned)(ed.x & 0xFFFF);
    }
    __syncthreads();

    // quarter-phased gather-reduce: q outer so each phase's support slice
    // (M x 32 cols = 3.2MB) stays L2-resident per XCD.
    const int eg = lane >> 4;            // edge slot 0..3 within batch
    const int cp = lane & 15;            // col-pair 0..15 within quarter
    for (int q = 0; q < 4; ++q) {
        const int qoff = q * 32 + cp * 2;
        for (int r = w; r < RPB; r += 4) {
            const int row = b * RPB + r;
            if (row >= M) continue;
            const int st = rs[r], e2 = rs[r + 1];
            float ax = 0.f, ay = 0.f;
            for (int i = st; i < e2; i += 8) {
                #pragma unroll
                for (int h = 0; h < 2; ++h) {
                    const int ib = i + h * 4;
                    if (ib < e2) {
                        const int m = e2 - ib;               // >= 1
                        const int idx = ib + (eg < m ? eg : m - 1);
                        const unsigned ed = rowList[idx];
                        const float v = (eg < m)
                            ? __builtin_bit_cast(float, ed & 0xFFFF0000u) : 0.f;
                        const unsigned p = *(const unsigned*)(
                            support + (size_t)(ed & 0xFFFFu) * D + qoff);
                        ax += __builtin_bit_cast(float, p << 16) * v;
                        ay += __builtin_bit_cast(float, p & 0xFFFF0000u) * v;
                    }
                }
            }
            // cross-group reduce (4 groups of 16 lanes hold same col-pair)
            ax += __shfl_xor(ax, 16); ay += __shfl_xor(ay, 16);
            ax += __shfl_xor(ax, 32); ay += __shfl_xor(ay, 32);
            if (eg == 0) {
                const unsigned pr = *(const unsigned*)(
                    rootbuf + (size_t)row * D + qoff);
                float2v ov;
                ov.x = ax + __builtin_bit_cast(float, pr << 16);
                ov.y = ay + __builtin_bit_cast(float, pr & 0xFFFF0000u);
                __builtin_nontemporal_store(ov,
                    (float2v*)(out + (size_t)row * D + qoff));
            }
        }
        __syncthreads();                 // keep block waves phase-coherent
    }
}

extern "C" void kernel_launch(void* const* d_in, const int* in_sizes, int n_in,
                              void* d_out, int out_size, void* d_ws, size_t ws_size,
                              hipStream_t stream) {
    const float* x     = (const float*)d_in[0];
    const int*   erows = (const int*)d_in[1];
    const int*   ecols = (const int*)d_in[2];
    const float* evals = (const float*)d_in[3];
    const float* W     = (const float*)d_in[4];
    const float* Wr    = (const float*)d_in[5];
    float* out = (float*)d_out;

    const int M = in_sizes[0] / D;   // 50000
    const int E = in_sizes[1];       // 800000

    const int nbuck = (M + RPB - 1) / RPB;         // 1563
    const int chunk = (E + NCK - 1) / NCK;         // 1563
    const int nGemm = (M + 63) / 64;               // 782

    // ws layout
    unsigned short* support = (unsigned short*)d_ws;            // M*D bf16
    unsigned short* rootbuf = support + (size_t)M * D;          // M*D bf16
    unsigned short* Wt      = rootbuf + (size_t)M * D;          // 2*D*D bf16
    unsigned* pkT   = (unsigned*)(Wt + 2 * D * D);              // NCK*nbuck
    unsigned* pkTt  = pkT + (size_t)NCK * nbuck;                // nbuck*NCK
    int2*  sortedB  = (int2*)(pkTt + (size_t)nbuck * NCK);      // NCK*chunk

    const int nTb = (nbuck + 63) / 64;             // 25

    wt_prep<<<128, 256, 0, stream>>>(W, Wr, Wt);
    prep_gemm<<<NCK + nGemm, 256, 0, stream>>>(
        erows, ecols, evals, pkT, sortedB, x, Wt, support, rootbuf,
        M, E, nbuck, chunk);
    transpose_pk<<<8 * nTb, 256, 0, stream>>>(pkT, pkTt, nbuck);
    sort_aggregate<<<nbuck, 256, 0, stream>>>(pkTt, sortedB,
                                              support, rootbuf, out, M, nbuck, chunk);
}

// Round 13
// 154.184 us; speedup vs baseline: 4.8940x; 1.3370x over previous
//
#include <hip/hip_runtime.h>

#define D 128
#define NCK 512           // edge chunks (binsort blocks in fused K1)
#define RPB 32            // rows per bucket
#define BCAP 1024         // per-bucket edge capacity (mean 512, +22 sigma)
#define SCANW 2048        // padded bucket-scan width (nbuck = 1563)
#define RAWB 17408        // union LDS: max(2*SCANW*4=16384, As 64*136*2=17408)

typedef short short8 __attribute__((ext_vector_type(8)));
typedef float v4f __attribute__((ext_vector_type(4)));
typedef float float2v __attribute__((ext_vector_type(2)));

static __device__ __forceinline__ unsigned short f2bf(float f) {
    unsigned u = __builtin_bit_cast(unsigned, f);
    u = (u + 0x7FFFu + ((u >> 16) & 1u)) >> 16;   // RNE
    return (unsigned short)u;
}

// ---- K0: Wt[n][k] = (W||Wr)[k][n] bf16 -------------------------------------
__global__ __launch_bounds__(256) void wt_prep(
    const float* __restrict__ W, const float* __restrict__ Wr,
    unsigned short* __restrict__ Wt)
{
    const int gid = (int)blockIdx.x * 256 + (int)threadIdx.x;   // < 32768
    const int k  = gid >> 8;
    const int nn = gid & 255;
    const float v = (nn < D) ? W[k * D + nn] : Wr[k * D + (nn - D)];
    Wt[nn * D + k] = f2bf(v);
}

// ---- K1: fused — blocks [0,NCK): per-chunk binsort (2-pass, direct global
//          writes: each chunk region is single-block-owned so partial stores
//          merge to full lines in that XCD's L2); rest: dual GEMM ------------
__global__ __launch_bounds__(256) void prep_gemm(
    const int* __restrict__ rows, const int* __restrict__ cols,
    const float* __restrict__ vals,
    unsigned* __restrict__ pkT, int2* __restrict__ sortedB,
    const float* __restrict__ x, const unsigned short* __restrict__ Wt,
    unsigned short* __restrict__ support, unsigned short* __restrict__ rootbuf,
    int M, int E, int nbuck, int chunk)
{
    __shared__ __align__(16) char raw[RAWB];
    __shared__ int wsumK[4];
    const int t = threadIdx.x;
    const int lane = t & 63, w = t >> 6;

    if ((int)blockIdx.x < NCK) {
        // ---------------- binsort branch (2 passes, no staging) -------------
        int* hist = (int*)raw;                       // SCANW
        int* cur  = hist + SCANW;                    // SCANW
        const int c = blockIdx.x;

        #pragma unroll
        for (int j = 0; j < SCANW / 256; ++j) hist[t + j * 256] = 0;
        __syncthreads();

        const int base = c * chunk;
        const int endv = min(base + chunk, E);
        for (int e = base + t; e < endv; e += 256)
            atomicAdd(&hist[rows[e] >> 5], 1);
        __syncthreads();

        // thread t owns 8 contiguous buckets [8t, 8t+8)
        int lv[8];
        int ssum = 0;
        #pragma unroll
        for (int j = 0; j < 8; ++j) { lv[j] = hist[8 * t + j]; ssum += lv[j]; }
        int s = ssum;                                // wave inclusive scan
        #pragma unroll
        for (int d = 1; d < 64; d <<= 1) {
            const int u = __shfl_up(s, d);
            if (lane >= d) s += u;
        }
        if (lane == 63) wsumK[w] = s;
        __syncthreads();
        int woff = 0;
        #pragma unroll
        for (int j = 0; j < 4; ++j) if (j < w) woff += wsumK[j];
        int run = woff + s - ssum;                   // exclusive base
        #pragma unroll
        for (int j = 0; j < 8; ++j) {
            const int idx = 8 * t + j;
            cur[idx] = run;
            if (idx < nbuck)
                pkT[(size_t)c * nbuck + idx] =
                    ((unsigned)lv[j] << 16) | (unsigned)run;
            run += lv[j];
        }
        __syncthreads();

        // pass 2: direct scattered store into block-private chunk region
        for (int e = base + t; e < endv; e += 256) {
            const int r  = rows[e];
            const int cc = cols[e];
            const float v = vals[e];
            const int pos = atomicAdd(&cur[r >> 5], 1);
            sortedB[(size_t)base + pos] =
                make_int2(((r & (RPB - 1)) << 16) | cc, __float_as_int(v));
        }
        return;
    }

    // ---------------- GEMM branch ----------------
    unsigned short (*As)[136] = (unsigned short (*)[136])raw;
    const int nl = lane & 15, quad = lane >> 4;
    const int rowBase = ((int)blockIdx.x - NCK) * 64;

    {
        const int r = t & 63;
        const int seg = t >> 6;
        const int row = rowBase + r;
        unsigned short tmp[32];
        if (row < M) {
            const float4* src = (const float4*)(x + (size_t)row * D + seg * 32);
            #pragma unroll
            for (int j = 0; j < 8; ++j) {
                const float4 v = src[j];
                tmp[j * 4 + 0] = f2bf(v.x); tmp[j * 4 + 1] = f2bf(v.y);
                tmp[j * 4 + 2] = f2bf(v.z); tmp[j * 4 + 3] = f2bf(v.w);
            }
        } else {
            #pragma unroll
            for (int j = 0; j < 32; ++j) tmp[j] = 0;
        }
        #pragma unroll
        for (int j = 0; j < 4; ++j)
            *(short8*)&As[r][seg * 32 + j * 8] = *(const short8*)&tmp[j * 8];
    }

    short8 bfrag[4][4];
    {
        const unsigned short* wbase = Wt + (size_t)(w * 64 + nl) * D + quad * 8;
        #pragma unroll
        for (int nt = 0; nt < 4; ++nt)
            #pragma unroll
            for (int c = 0; c < 4; ++c)
                bfrag[c][nt] = *(const short8*)(wbase + (size_t)nt * 16 * D + c * 32);
    }
    __syncthreads();

    v4f acc[4][4] = {};
    #pragma unroll
    for (int c = 0; c < 4; ++c) {
        short8 afr[4];
        #pragma unroll
        for (int mt = 0; mt < 4; ++mt)
            afr[mt] = *(const short8*)&As[mt * 16 + nl][c * 32 + quad * 8];
        #pragma unroll
        for (int mt = 0; mt < 4; ++mt)
            #pragma unroll
            for (int nt = 0; nt < 4; ++nt)
                acc[mt][nt] = __builtin_amdgcn_mfma_f32_16x16x32_bf16(
                    afr[mt], bfrag[c][nt], acc[mt][nt], 0, 0, 0);
    }

    const int cbase = (w & 1) * 64;
    unsigned short* dst = (w < 2) ? support : rootbuf;
    #pragma unroll
    for (int mt = 0; mt < 4; ++mt)
        #pragma unroll
        for (int reg = 0; reg < 4; ++reg) {
            const int row = rowBase + mt * 16 + quad * 4 + reg;
            if (row < M) {
                #pragma unroll
                for (int nt = 0; nt < 4; ++nt)
                    dst[(size_t)row * D + cbase + nt * 16 + nl] = f2bf(acc[mt][nt][reg]);
            }
        }
}

// ---- K1.5: transpose pkT[c][b] -> pkTt[b][c] (coalesced both sides) --------
__global__ __launch_bounds__(256) void transpose_pk(
    const unsigned* __restrict__ pkT, unsigned* __restrict__ pkTt, int nbuck)
{
    __shared__ unsigned tile[64][65];
    const int cb = (int)blockIdx.x & 7;          // NCK/64 = 8
    const int bb = (int)blockIdx.x >> 3;
    const int t = threadIdx.x;
    for (int i = t; i < 64 * 64; i += 256) {
        const int lc = i & 63, lr = i >> 6;
        const int b = bb * 64 + lc, c = cb * 64 + lr;
        tile[lr][lc] = (b < nbuck) ? pkT[(size_t)c * nbuck + b] : 0u;
    }
    __syncthreads();
    for (int i = t; i < 64 * 64; i += 256) {
        const int lc = i & 63, lr = i >> 6;
        const int b = bb * 64 + lr, c = cb * 64 + lc;
        if (b < nbuck) pkTt[(size_t)b * NCK + c] = tile[lc][lr];
    }
}

// ---- K2: per-bucket (32 rows): stage -> LDS row-sort -> batch-16 gather ----
__global__ __launch_bounds__(256) void sort_aggregate(
    const unsigned* __restrict__ pkTt, const int2* __restrict__ sortedB,
    const unsigned short* __restrict__ support,
    const unsigned short* __restrict__ rootbuf,
    float* __restrict__ out, int M, int nbuck, int chunk)
{
    __shared__ int2 stage[BCAP];        // 8 KB
    __shared__ unsigned rowList[BCAP];  // 4 KB
    __shared__ int wsum[4];
    __shared__ int rh[RPB];
    __shared__ int rs[RPB + 1];
    __shared__ int rcur[RPB];
    const int b = blockIdx.x, t = threadIdx.x;
    const int lane = t & 63, w = t >> 6;

    // coalesced table read: thread t owns chunks 2t, 2t+1
    const uint2 pk2 = *(const uint2*)(pkTt + (size_t)b * NCK + 2 * t);
    const int cnt0 = (int)(pk2.x >> 16), off0 = (int)(pk2.x & 0xFFFFu);
    const int cnt1 = (int)(pk2.y >> 16), off1 = (int)(pk2.y & 0xFFFFu);
    int s = cnt0 + cnt1;                 // wave inclusive scan over pair-sums
    #pragma unroll
    for (int d = 1; d < 64; d <<= 1) {
        const int u = __shfl_up(s, d);
        if (lane >= d) s += u;
    }
    if (lane == 63) wsum[w] = s;
    __syncthreads();
    int woff = 0, tot = 0;
    #pragma unroll
    for (int j = 0; j < 4; ++j) { const int v = wsum[j]; if (j < w) woff += v; tot += v; }
    const int incl = woff + s;
    const int base1 = incl - cnt1;
    const int base0 = base1 - cnt0;
    {
        const int2* src = sortedB + (size_t)(2 * t) * chunk + off0;
        int lim = min(base0 + cnt0, BCAP) - base0; if (lim < 0) lim = 0;
        for (int k = 0; k < lim; ++k) stage[base0 + k] = src[k];
    }
    {
        const int2* src = sortedB + (size_t)(2 * t + 1) * chunk + off1;
        int lim = min(base1 + cnt1, BCAP) - base1; if (lim < 0) lim = 0;
        for (int k = 0; k < lim; ++k) stage[base1 + k] = src[k];
    }
    if (t < RPB) rh[t] = 0;
    __syncthreads();

    const int T = min(tot, BCAP);
    for (int e = t; e < T; e += 256) atomicAdd(&rh[stage[e].x >> 16], 1);
    __syncthreads();
    if (t < 64) {                        // row scan (32 wide) in first wave
        const int mine = (t < RPB) ? rh[t] : 0;
        int v = mine;
        #pragma unroll
        for (int d = 1; d < RPB; d <<= 1) {
            const int u = __shfl_up(v, d);
            if (lane >= d) v += u;
        }
        if (t < RPB) {
            rs[t] = v - mine; rcur[t] = v - mine;
            if (t == RPB - 1) rs[RPB] = v;
        }
    }
    __syncthreads();
    for (int e = t; e < T; e += 256) {
        const int2 ed = stage[e];
        const int rib = ed.x >> 16;
        const int pos = atomicAdd(&rcur[rib], 1);
        rowList[pos] = ((unsigned)f2bf(__int_as_float(ed.y)) << 16)
                     | (unsigned)(ed.x & 0xFFFF);
    }
    __syncthreads();

    // per-row gather-reduce: wave w handles rows w, w+4, ... (batch-16 core)
    for (int r = w; r < RPB; r += 4) {
        const int row = b * RPB + r;
        if (row >= M) continue;
        const int st = rs[r], e2 = rs[r + 1];
        float ax = 0.f, ay = 0.f;
        int i = st;

        for (; i + 16 <= e2; i += 16) {
            unsigned d[16];
            #pragma unroll
            for (int j = 0; j < 16; ++j) d[j] = rowList[i + j];
            unsigned p[16];
            #pragma unroll
            for (int j = 0; j < 16; ++j)
                p[j] = *(const unsigned*)(support + (size_t)(d[j] & 0xFFFF) * D + lane * 2);
            #pragma unroll
            for (int j = 0; j < 16; ++j) {
                const float v = __builtin_bit_cast(float, d[j] & 0xFFFF0000u);
                ax += __builtin_bit_cast(float, p[j] << 16) * v;
                ay += __builtin_bit_cast(float, p[j] & 0xFFFF0000u) * v;
            }
        }
        if (i + 8 <= e2) {
            unsigned d[8];
            #pragma unroll
            for (int j = 0; j < 8; ++j) d[j] = rowList[i + j];
            unsigned p[8];
            #pragma unroll
            for (int j = 0; j < 8; ++j)
                p[j] = *(const unsigned*)(support + (size_t)(d[j] & 0xFFFF) * D + lane * 2);
            #pragma unroll
            for (int j = 0; j < 8; ++j) {
                const float v = __builtin_bit_cast(float, d[j] & 0xFFFF0000u);
                ax += __builtin_bit_cast(float, p[j] << 16) * v;
                ay += __builtin_bit_cast(float, p[j] & 0xFFFF0000u) * v;
            }
            i += 8;
        }
        if (i < e2) {
            const int m = e2 - i;   // 1..7
            unsigned d[8];
            #pragma unroll
            for (int j = 0; j < 8; ++j) {
                const int idx = i + (j < m ? j : m - 1);
                const unsigned q = rowList[idx];
                d[j] = (j < m) ? q : (q & 0xFFFFu);   // zero val for pads
            }
            unsigned p[8];
            #pragma unroll
            for (int j = 0; j < 8; ++j)
                p[j] = *(const unsigned*)(support + (size_t)(d[j] & 0xFFFF) * D + lane * 2);
            #pragma unroll
            for (int j = 0; j < 8; ++j) {
                const float v = __builtin_bit_cast(float, d[j] & 0xFFFF0000u);
                ax += __builtin_bit_cast(float, p[j] << 16) * v;
                ay += __builtin_bit_cast(float, p[j] & 0xFFFF0000u) * v;
            }
        }

        const unsigned pr = *(const unsigned*)(rootbuf + (size_t)row * D + lane * 2);
        float2v ov;
        ov.x = ax + __builtin_bit_cast(float, pr << 16);
        ov.y = ay + __builtin_bit_cast(float, pr & 0xFFFF0000u);
        __builtin_nontemporal_store(ov, (float2v*)(out + (size_t)row * D + lane * 2));
    }
}

extern "C" void kernel_launch(void* const* d_in, const int* in_sizes, int n_in,
                              void* d_out, int out_size, void* d_ws, size_t ws_size,
                              hipStream_t stream) {
    const float* x     = (const float*)d_in[0];
    const int*   erows = (const int*)d_in[1];
    const int*   ecols = (const int*)d_in[2];
    const float* evals = (const float*)d_in[3];
    const float* W     = (const float*)d_in[4];
    const float* Wr    = (const float*)d_in[5];
    float* out = (float*)d_out;

    const int M = in_sizes[0] / D;   // 50000
    const int E = in_sizes[1];       // 800000

    const int nbuck = (M + RPB - 1) / RPB;         // 1563
    const int chunk = (E + NCK - 1) / NCK;         // 1563
    const int nGemm = (M + 63) / 64;               // 782

    // ws layout
    unsigned short* support = (unsigned short*)d_ws;            // M*D bf16
    unsigned short* rootbuf = support + (size_t)M * D;          // M*D bf16
    unsigned short* Wt      = rootbuf + (size_t)M * D;          // 2*D*D bf16
    unsigned* pkT   = (unsigned*)(Wt + 2 * D * D);              // NCK*nbuck
    unsigned* pkTt  = pkT + (size_t)NCK * nbuck;                // nbuck*NCK
    int2*  sortedB  = (int2*)(pkTt + (size_t)nbuck * NCK);      // NCK*chunk

    const int nTb = (nbuck + 63) / 64;             // 25

    wt_prep<<<128, 256, 0, stream>>>(W, Wr, Wt);
    prep_gemm<<<NCK + nGemm, 256, 0, stream>>>(
        erows, ecols, evals, pkT, sortedB, x, Wt, support, rootbuf,
        M, E, nbuck, chunk);
    transpose_pk<<<8 * nTb, 256, 0, stream>>>(pkT, pkTt, nbuck);
    sort_aggregate<<<nbuck, 256, 0, stream>>>(pkTt, sortedB,
                                              support, rootbuf, out, M, nbuck, chunk);
}

// Round 14
// 148.369 us; speedup vs baseline: 5.0858x; 1.0392x over previous
//
#include <hip/hip_runtime.h>

#define D 128
#define NCK 256           // edge chunks (binsort blocks in fused K1)
#define RPB 32            // rows per bucket
#define BCAP 1024         // per-bucket edge capacity (mean 512, +22 sigma)
#define SCANW 2048        // padded bucket-scan width (nbuck = 1563)
#define RAWB 17408        // union LDS: max(2*SCANW*4=16384, As 64*136*2=17408)

typedef short short8 __attribute__((ext_vector_type(8)));
typedef float v4f __attribute__((ext_vector_type(4)));
typedef float float2v __attribute__((ext_vector_type(2)));

static __device__ __forceinline__ unsigned short f2bf(float f) {
    unsigned u = __builtin_bit_cast(unsigned, f);
    u = (u + 0x7FFFu + ((u >> 16) & 1u)) >> 16;   // RNE
    return (unsigned short)u;
}

// ---- K0: Wt[n][k] = (W||Wr)[k][n] bf16 -------------------------------------
__global__ __launch_bounds__(256) void wt_prep(
    const float* __restrict__ W, const float* __restrict__ Wr,
    unsigned short* __restrict__ Wt)
{
    const int gid = (int)blockIdx.x * 256 + (int)threadIdx.x;   // < 32768
    const int k  = gid >> 8;
    const int nn = gid & 255;
    const float v = (nn < D) ? W[k * D + nn] : Wr[k * D + (nn - D)];
    Wt[nn * D + k] = f2bf(v);
}

// ---- K1: fused — blocks [0,NCK): per-chunk binsort (direct global stores,
//          chunk id XCD-swizzled so all writers of one pkTt line share an
//          XCD and merge in its L2); rest: dual GEMM ------------------------
__global__ __launch_bounds__(256) void prep_gemm(
    const int* __restrict__ rows, const int* __restrict__ cols,
    const float* __restrict__ vals,
    unsigned* __restrict__ pkTt, int2* __restrict__ sortedB,
    const float* __restrict__ x, const unsigned short* __restrict__ Wt,
    unsigned short* __restrict__ support, unsigned short* __restrict__ rootbuf,
    int M, int E, int nbuck, int chunk)
{
    __shared__ __align__(16) char raw[RAWB];
    __shared__ int wsumK[4];
    const int t = threadIdx.x;
    const int lane = t & 63, w = t >> 6;

    if ((int)blockIdx.x < NCK) {
        // ---------------- binsort branch (2 passes, no staging) -------------
        int* hist = (int*)raw;                       // SCANW
        int* cur  = hist + SCANW;                    // SCANW
        // XCD-coherent chunk mapping: pkTt line (16 chunks) -> one bid%8 class
        const int c = (((int)blockIdx.x & 7) << 5) + ((int)blockIdx.x >> 3);

        #pragma unroll
        for (int j = 0; j < SCANW / 256; ++j) hist[t + j * 256] = 0;
        __syncthreads();

        const int base = c * chunk;
        const int endv = min(base + chunk, E);
        for (int e = base + t; e < endv; e += 256)
            atomicAdd(&hist[rows[e] >> 5], 1);
        __syncthreads();

        // thread t owns 8 contiguous buckets [8t, 8t+8)
        int lv[8];
        int ssum = 0;
        #pragma unroll
        for (int j = 0; j < 8; ++j) { lv[j] = hist[8 * t + j]; ssum += lv[j]; }
        int s = ssum;                                // wave inclusive scan
        #pragma unroll
        for (int d = 1; d < 64; d <<= 1) {
            const int u = __shfl_up(s, d);
            if (lane >= d) s += u;
        }
        if (lane == 63) wsumK[w] = s;
        __syncthreads();
        int woff = 0;
        #pragma unroll
        for (int j = 0; j < 4; ++j) if (j < w) woff += wsumK[j];
        int run = woff + s - ssum;                   // exclusive base
        #pragma unroll
        for (int j = 0; j < 8; ++j) {
            const int idx = 8 * t + j;
            cur[idx] = run;
            if (idx < nbuck)
                pkTt[(size_t)idx * NCK + c] =        // direct transposed write
                    ((unsigned)lv[j] << 16) | (unsigned)run;
            run += lv[j];
        }
        __syncthreads();

        // pass 2: direct scattered store into block-private chunk region
        for (int e = base + t; e < endv; e += 256) {
            const int r  = rows[e];
            const int cc = cols[e];
            const float v = vals[e];
            const int pos = atomicAdd(&cur[r >> 5], 1);
            sortedB[(size_t)base + pos] =
                make_int2(((r & (RPB - 1)) << 16) | cc, __float_as_int(v));
        }
        return;
    }

    // ---------------- GEMM branch ----------------
    unsigned short (*As)[136] = (unsigned short (*)[136])raw;
    const int nl = lane & 15, quad = lane >> 4;
    const int rowBase = ((int)blockIdx.x - NCK) * 64;

    {
        const int r = t & 63;
        const int seg = t >> 6;
        const int row = rowBase + r;
        unsigned short tmp[32];
        if (row < M) {
            const float4* src = (const float4*)(x + (size_t)row * D + seg * 32);
            #pragma unroll
            for (int j = 0; j < 8; ++j) {
                const float4 v = src[j];
                tmp[j * 4 + 0] = f2bf(v.x); tmp[j * 4 + 1] = f2bf(v.y);
                tmp[j * 4 + 2] = f2bf(v.z); tmp[j * 4 + 3] = f2bf(v.w);
            }
        } else {
            #pragma unroll
            for (int j = 0; j < 32; ++j) tmp[j] = 0;
        }
        #pragma unroll
        for (int j = 0; j < 4; ++j)
            *(short8*)&As[r][seg * 32 + j * 8] = *(const short8*)&tmp[j * 8];
    }

    short8 bfrag[4][4];
    {
        const unsigned short* wbase = Wt + (size_t)(w * 64 + nl) * D + quad * 8;
        #pragma unroll
        for (int nt = 0; nt < 4; ++nt)
            #pragma unroll
            for (int c = 0; c < 4; ++c)
                bfrag[c][nt] = *(const short8*)(wbase + (size_t)nt * 16 * D + c * 32);
    }
    __syncthreads();

    v4f acc[4][4] = {};
    #pragma unroll
    for (int c = 0; c < 4; ++c) {
        short8 afr[4];
        #pragma unroll
        for (int mt = 0; mt < 4; ++mt)
            afr[mt] = *(const short8*)&As[mt * 16 + nl][c * 32 + quad * 8];
        #pragma unroll
        for (int mt = 0; mt < 4; ++mt)
            #pragma unroll
            for (int nt = 0; nt < 4; ++nt)
                acc[mt][nt] = __builtin_amdgcn_mfma_f32_16x16x32_bf16(
                    afr[mt], bfrag[c][nt], acc[mt][nt], 0, 0, 0);
    }

    const int cbase = (w & 1) * 64;
    unsigned short* dst = (w < 2) ? support : rootbuf;
    #pragma unroll
    for (int mt = 0; mt < 4; ++mt)
        #pragma unroll
        for (int reg = 0; reg < 4; ++reg) {
            const int row = rowBase + mt * 16 + quad * 4 + reg;
            if (row < M) {
                #pragma unroll
                for (int nt = 0; nt < 4; ++nt)
                    dst[(size_t)row * D + cbase + nt * 16 + nl] = f2bf(acc[mt][nt][reg]);
            }
        }
}

// ---- K2: per-bucket (32 rows): stage -> LDS row-sort -> batch-16 gather ----
__global__ __launch_bounds__(256) void sort_aggregate(
    const unsigned* __restrict__ pkTt, const int2* __restrict__ sortedB,
    const unsigned short* __restrict__ support,
    const unsigned short* __restrict__ rootbuf,
    float* __restrict__ out, int M, int nbuck, int chunk)
{
    __shared__ int2 stage[BCAP];        // 8 KB
    __shared__ unsigned rowList[BCAP];  // 4 KB
    __shared__ int wsum[4];
    __shared__ int rh[RPB];
    __shared__ int rs[RPB + 1];
    __shared__ int rcur[RPB];
    const int b = blockIdx.x, t = threadIdx.x;
    const int lane = t & 63, w = t >> 6;

    // coalesced table read: thread t owns chunk t (1 KB contiguous row)
    const unsigned pk = pkTt[(size_t)b * NCK + t];
    const int cnt = (int)(pk >> 16), off = (int)(pk & 0xFFFFu);
    int s = cnt;                         // wave inclusive scan
    #pragma unroll
    for (int d = 1; d < 64; d <<= 1) {
        const int u = __shfl_up(s, d);
        if (lane >= d) s += u;
    }
    if (lane == 63) wsum[w] = s;
    __syncthreads();
    int woff = 0, tot = 0;
    #pragma unroll
    for (int j = 0; j < 4; ++j) { const int v = wsum[j]; if (j < w) woff += v; tot += v; }
    const int base0 = woff + s - cnt;
    {
        const int2* src = sortedB + (size_t)t * chunk + off;
        int lim = min(base0 + cnt, BCAP) - base0; if (lim < 0) lim = 0;
        for (int k = 0; k < lim; ++k) stage[base0 + k] = src[k];
    }
    if (t < RPB) rh[t] = 0;
    __syncthreads();

    const int T = min(tot, BCAP);
    for (int e = t; e < T; e += 256) atomicAdd(&rh[stage[e].x >> 16], 1);
    __syncthreads();
    if (t < 64) {                        // row scan (32 wide) in first wave
        const int mine = (t < RPB) ? rh[t] : 0;
        int v = mine;
        #pragma unroll
        for (int d = 1; d < RPB; d <<= 1) {
            const int u = __shfl_up(v, d);
            if (lane >= d) v += u;
        }
        if (t < RPB) {
            rs[t] = v - mine; rcur[t] = v - mine;
            if (t == RPB - 1) rs[RPB] = v;
        }
    }
    __syncthreads();
    for (int e = t; e < T; e += 256) {
        const int2 ed = stage[e];
        const int rib = ed.x >> 16;
        const int pos = atomicAdd(&rcur[rib], 1);
        rowList[pos] = ((unsigned)f2bf(__int_as_float(ed.y)) << 16)
                     | (unsigned)(ed.x & 0xFFFF);
    }
    __syncthreads();

    // per-row gather-reduce: wave w handles rows w, w+4, ... (batch-16 core)
    for (int r = w; r < RPB; r += 4) {
        const int row = b * RPB + r;
        if (row >= M) continue;
        const int st = rs[r], e2 = rs[r + 1];
        float ax = 0.f, ay = 0.f;
        int i = st;

        for (; i + 16 <= e2; i += 16) {
            unsigned d[16];
            #pragma unroll
            for (int j = 0; j < 16; ++j) d[j] = rowList[i + j];
            unsigned p[16];
            #pragma unroll
            for (int j = 0; j < 16; ++j)
                p[j] = *(const unsigned*)(support + (size_t)(d[j] & 0xFFFF) * D + lane * 2);
            #pragma unroll
            for (int j = 0; j < 16; ++j) {
                const float v = __builtin_bit_cast(float, d[j] & 0xFFFF0000u);
                ax += __builtin_bit_cast(float, p[j] << 16) * v;
                ay += __builtin_bit_cast(float, p[j] & 0xFFFF0000u) * v;
            }
        }
        if (i + 8 <= e2) {
            unsigned d[8];
            #pragma unroll
            for (int j = 0; j < 8; ++j) d[j] = rowList[i + j];
            unsigned p[8];
            #pragma unroll
            for (int j = 0; j < 8; ++j)
                p[j] = *(const unsigned*)(support + (size_t)(d[j] & 0xFFFF) * D + lane * 2);
            #pragma unroll
            for (int j = 0; j < 8; ++j) {
                const float v = __builtin_bit_cast(float, d[j] & 0xFFFF0000u);
                ax += __builtin_bit_cast(float, p[j] << 16) * v;
                ay += __builtin_bit_cast(float, p[j] & 0xFFFF0000u) * v;
            }
            i += 8;
        }
        if (i < e2) {
            const int m = e2 - i;   // 1..7
            unsigned d[8];
            #pragma unroll
            for (int j = 0; j < 8; ++j) {
                const int idx = i + (j < m ? j : m - 1);
                const unsigned q = rowList[idx];
                d[j] = (j < m) ? q : (q & 0xFFFFu);   // zero val for pads
            }
            unsigned p[8];
            #pragma unroll
            for (int j = 0; j < 8; ++j)
                p[j] = *(const unsigned*)(support + (size_t)(d[j] & 0xFFFF) * D + lane * 2);
            #pragma unroll
            for (int j = 0; j < 8; ++j) {
                const float v = __builtin_bit_cast(float, d[j] & 0xFFFF0000u);
                ax += __builtin_bit_cast(float, p[j] << 16) * v;
                ay += __builtin_bit_cast(float, p[j] & 0xFFFF0000u) * v;
            }
        }

        const unsigned pr = *(const unsigned*)(rootbuf + (size_t)row * D + lane * 2);
        float2v ov;
        ov.x = ax + __builtin_bit_cast(float, pr << 16);
        ov.y = ay + __builtin_bit_cast(float, pr & 0xFFFF0000u);
        __builtin_nontemporal_store(ov, (float2v*)(out + (size_t)row * D + lane * 2));
    }
}

extern "C" void kernel_launch(void* const* d_in, const int* in_sizes, int n_in,
                              void* d_out, int out_size, void* d_ws, size_t ws_size,
                              hipStream_t stream) {
    const float* x     = (const float*)d_in[0];
    const int*   erows = (const int*)d_in[1];
    const int*   ecols = (const int*)d_in[2];
    const float* evals = (const float*)d_in[3];
    const float* W     = (const float*)d_in[4];
    const float* Wr    = (const float*)d_in[5];
    float* out = (float*)d_out;

    const int M = in_sizes[0] / D;   // 50000
    const int E = in_sizes[1];       // 800000

    const int nbuck = (M + RPB - 1) / RPB;         // 1563
    const int chunk = (E + NCK - 1) / NCK;         // 3125
    const int nGemm = (M + 63) / 64;               // 782

    // ws layout
    unsigned short* support = (unsigned short*)d_ws;            // M*D bf16
    unsigned short* rootbuf = support + (size_t)M * D;          // M*D bf16
    unsigned short* Wt      = rootbuf + (size_t)M * D;          // 2*D*D bf16
    unsigned* pkTt  = (unsigned*)(Wt + 2 * D * D);              // nbuck*NCK
    int2*  sortedB  = (int2*)(pkTt + (size_t)nbuck * NCK);      // NCK*chunk

    wt_prep<<<128, 256, 0, stream>>>(W, Wr, Wt);
    prep_gemm<<<NCK + nGemm, 256, 0, stream>>>(
        erows, ecols, evals, pkTt, sortedB, x, Wt, support, rootbuf,
        M, E, nbuck, chunk);
    sort_aggregate<<<nbuck, 256, 0, stream>>>(pkTt, sortedB,
                                              support, rootbuf, out, M, nbuck, chunk);
}